// Round 2
// baseline (446.781 us; speedup 1.0000x reference)
//
#include <hip/hip_runtime.h>
#include <hip/hip_fp16.h>

// CommNet critic forward, fused: 1 WG (256 thr, 4 waves) = 1 batch (32 agents).
// GEMMs via v_mfma_f32_16x16x32_f16 (fp32 acc). B=2048, A=32, D=128, H=256.
// R2: 4 WGs/CU (4 barrier domains), 4 ntiles/wave (2x A-reuse), 2 LDS act buffers,
//     chained-MFMA GRU2 gates, coalesced prep kernel.

#define NB   2048
#define NA   32
#define DIN  128
#define HID  256
#define SA   264   // f16 row stride for activation LDS tiles

typedef _Float16 half8  __attribute__((ext_vector_type(8)));
typedef _Float16 half4_t __attribute__((ext_vector_type(4)));
typedef float    float4v __attribute__((ext_vector_type(4)));

// f16 weight-fragment arena in d_ws (element offsets)
#define ENC_OFF    0
#define FOBS_OFF   32768
#define WIH_OFF    98304
#define WHH_OFF    294912
#define PREP_TOTAL 491520   // f16 elements -> 983040 bytes

// One wave per (matrix, ks, nt) fragment tile: reads a 16-row x 32-k fp32 block
// (2x float4 per lane), writes one coalesced half8 per lane.
// frag[((ks*NT + nt)*64 + lane)*8 + j] = W[nt*16 + lane%16][ks*32 + (lane/16)*8 + j]
__global__ __launch_bounds__(256) void prep_weights(
        const float* __restrict__ encW, const float* __restrict__ fobsW,
        const float* __restrict__ wih,  const float* __restrict__ whh,
        _Float16* __restrict__ prep) {
    int W = blockIdx.x * 4 + (threadIdx.x >> 6);   // global wave id, 0..959
    int lane = threadIdx.x & 63;
    const float* src; int K, NT, base, idx;
    if (W < 64)       { src = encW;  K = 128; NT = 16; base = ENC_OFF;  idx = W; }
    else if (W < 192) { src = fobsW; K = 256; NT = 16; base = FOBS_OFF; idx = W - 64; }
    else if (W < 576) { src = wih;   K = 256; NT = 48; base = WIH_OFF;  idx = W - 192; }
    else              { src = whh;   K = 256; NT = 48; base = WHH_OFF;  idx = W - 576; }
    int nt = idx % NT, ks = idx / NT;
    int l16 = lane & 15, q = lane >> 4;
    const float* s = src + (size_t)(nt * 16 + l16) * K + ks * 32 + q * 8;
    float4v f0 = *(const float4v*)s;
    float4v f1 = *(const float4v*)(s + 4);
    half8 h;
    h[0] = (_Float16)f0[0]; h[1] = (_Float16)f0[1]; h[2] = (_Float16)f0[2]; h[3] = (_Float16)f0[3];
    h[4] = (_Float16)f1[0]; h[5] = (_Float16)f1[1]; h[6] = (_Float16)f1[2]; h[7] = (_Float16)f1[3];
    *(half8*)(prep + base + (((size_t)(ks * NT + nt) * 64 + lane) << 3)) = h;
}

__device__ __forceinline__ float sigmoid_f(float x) {
    x = fminf(fmaxf(x, -30.f), 30.f);
    return 1.f / (1.f + __expf(-x));
}
__device__ __forceinline__ float tanh_f(float x) {
    x = fminf(fmaxf(x, -15.f), 15.f);
    float e = __expf(-2.f * x);
    return (1.f - e) / (1.f + e);
}

__device__ __forceinline__ void zero24(float4v a[2][4]) {
    float4v z = {0.f, 0.f, 0.f, 0.f};
    #pragma unroll
    for (int m = 0; m < 2; m++)
        #pragma unroll
        for (int n = 0; n < 4; n++) a[m][n] = z;
}

// One wave: [32 rows] x [4 ntiles = 64 cols]. A from LDS (stride SA), B from
// prepped fragments (global, L2-resident) or raw fp32 fallback. Accumulates
// into acc (callers may chain multiple A/B products into one acc).
template<int KSTEPS>
__device__ __forceinline__ void gemm_tile4(const _Float16* __restrict__ Abuf,
        const _Float16* __restrict__ prepm, int NT, int ntg0,
        const float* __restrict__ raw, int K, int use_prep,
        int lane, float4v acc[2][4])
{
    const int l16 = lane & 15;
    const int kq  = (lane >> 4) << 3;
    #pragma unroll
    for (int ks = 0; ks < KSTEPS; ks++) {
        int kbase = ks * 32 + kq;
        half8 a0 = *(const half8*)(Abuf + l16 * SA + kbase);
        half8 a1 = *(const half8*)(Abuf + (16 + l16) * SA + kbase);
        #pragma unroll
        for (int nn = 0; nn < 4; nn++) {
            half8 b;
            if (use_prep) {
                b = *(const half8*)(prepm + (((ks * NT + ntg0 + nn) * 64 + lane) << 3));
            } else {
                #pragma unroll
                for (int j = 0; j < 8; j++)
                    b[j] = (_Float16)raw[((ntg0 + nn) * 16 + l16) * K + kbase + j];
            }
            acc[0][nn] = __builtin_amdgcn_mfma_f32_16x16x32_f16(a0, b, acc[0][nn], 0, 0, 0);
            acc[1][nn] = __builtin_amdgcn_mfma_f32_16x16x32_f16(a1, b, acc[1][nn], 0, 0, 0);
        }
    }
}

__global__ __launch_bounds__(256, 4) void commnet_fused(
    const float* __restrict__ obs, const _Float16* __restrict__ prep,
    const float* __restrict__ enc_b, const float* __restrict__ fobs_b,
    const float* __restrict__ b_ih, const float* __restrict__ b_hh,
    const float* __restrict__ dec_W, const float* __restrict__ dec_b,
    float* __restrict__ out,
    const float* __restrict__ encW, const float* __restrict__ fobsW,
    const float* __restrict__ wih, const float* __restrict__ whh,
    int use_prep)
{
    const int b    = blockIdx.x;
    const int tid  = threadIdx.x;
    const int lane = tid & 63;
    const int w    = tid >> 6;     // wave 0..3
    const int l16  = lane & 15;
    const int quad = lane >> 4;
    const int ntl0 = w * 4;        // this wave's 4 ntiles within 16 (256 cols)

    __shared__ __align__(16) _Float16 sA[2][NA * SA];
    __shared__ float S[HID];
    __shared__ float D[NA];

    // ---- stage obs (fp32 -> f16 LDS sA[0]); zero S, D
    const float* obsb = obs + (size_t)b * NA * DIN;
    #pragma unroll
    for (int j = 0; j < 4; j++) {
        int i = tid + j * 256;             // float4 index, 1024 total
        float4v v = ((const float4v*)obsb)[i];
        int r = i >> 5, kd = (i & 31) * 4;
        half4_t hv;
        hv[0] = (_Float16)v[0]; hv[1] = (_Float16)v[1];
        hv[2] = (_Float16)v[2]; hv[3] = (_Float16)v[3];
        *(half4_t*)(&sA[0][r * SA + kd]) = hv;
    }
    if (tid < HID) S[tid] = 0.f;
    if (tid < NA)  D[tid] = 0.f;
    __syncthreads();

    float4v acc[2][4];
    float rn[2][4][4];

    // ---- encoder: e = relu(obs @ encW^T + enc_b) -> sA[1]
    zero24(acc);
    gemm_tile4<4>(&sA[0][0], prep + ENC_OFF, 16, ntl0, encW, DIN, use_prep, lane, acc);
    #pragma unroll
    for (int nn = 0; nn < 4; nn++) {
        int col = (ntl0 + nn) * 16 + l16;
        float bb = enc_b[col];
        #pragma unroll
        for (int mt = 0; mt < 2; mt++)
            #pragma unroll
            for (int r = 0; r < 4; r++) {
                int row = mt * 16 + quad * 4 + r;
                sA[1][row * SA + col] = (_Float16)fmaxf(acc[mt][nn][r] + bb, 0.f);
            }
    }
    __syncthreads();

    // ---- fobs: h = e @ fobsW^T + fobs_b -> sA[0] (obs dead)
    zero24(acc);
    gemm_tile4<8>(&sA[1][0], prep + FOBS_OFF, 16, ntl0, fobsW, HID, use_prep, lane, acc);
    #pragma unroll
    for (int nn = 0; nn < 4; nn++) {
        int col = (ntl0 + nn) * 16 + l16;
        float bb = fobs_b[col];
        #pragma unroll
        for (int mt = 0; mt < 2; mt++)
            #pragma unroll
            for (int r = 0; r < 4; r++) {
                int row = mt * 16 + quad * 4 + r;
                sA[0][row * SA + col] = (_Float16)(acc[mt][nn][r] + bb);
            }
    }
    __syncthreads();

    // ---- GRU1 (x=0 => gi = b_ih). A = sA[0] (h). gate ntile bases: r=0, z=16, n=32
    zero24(acc);
    gemm_tile4<8>(&sA[0][0], prep + WHH_OFF, 48, 0 + ntl0, whh, HID, use_prep, lane, acc);
    #pragma unroll
    for (int nn = 0; nn < 4; nn++) {
        int col = (ntl0 + nn) * 16 + l16;
        float bi = b_ih[col], bh = b_hh[col];
        #pragma unroll
        for (int mt = 0; mt < 2; mt++)
            #pragma unroll
            for (int r = 0; r < 4; r++)
                rn[mt][nn][r] = sigmoid_f(bi + acc[mt][nn][r] + bh);   // r-gate
    }
    zero24(acc);
    gemm_tile4<8>(&sA[0][0], prep + WHH_OFF, 48, 32 + ntl0, whh, HID, use_prep, lane, acc);
    #pragma unroll
    for (int nn = 0; nn < 4; nn++) {
        int col = (ntl0 + nn) * 16 + l16;
        float bi = b_ih[512 + col], bh = b_hh[512 + col];
        #pragma unroll
        for (int mt = 0; mt < 2; mt++)
            #pragma unroll
            for (int r = 0; r < 4; r++)
                rn[mt][nn][r] = tanh_f(bi + rn[mt][nn][r] * (acc[mt][nn][r] + bh));  // n-gate
    }
    zero24(acc);
    gemm_tile4<8>(&sA[0][0], prep + WHH_OFF, 48, 16 + ntl0, whh, HID, use_prep, lane, acc);
    #pragma unroll
    for (int nn = 0; nn < 4; nn++) {
        int col = (ntl0 + nn) * 16 + l16;
        float bi = b_ih[256 + col], bh = b_hh[256 + col];
        float ssum = 0.f;
        #pragma unroll
        for (int mt = 0; mt < 2; mt++)
            #pragma unroll
            for (int r = 0; r < 4; r++) {
                int row = mt * 16 + quad * 4 + r;
                float z = sigmoid_f(bi + acc[mt][nn][r] + bh);
                float hold = (float)sA[0][row * SA + col];
                float h1 = (1.f - z) * rn[mt][nn][r] + z * hold;
                sA[1][row * SA + col] = (_Float16)h1;   // h1 -> sA[1] (e dead)
                ssum += h1;
            }
        atomicAdd(&S[col], ssum);                       // column sums for comm
    }
    __syncthreads();

    // ---- comm: c = (S - h1)/32 -> sA[0] (h dead)
    #pragma unroll
    for (int j = 0; j < 8; j++) {
        int i = tid + j * 256;             // half4 groups, 2048 total
        int r = i >> 6, cg = (i & 63) * 4;
        half4_t hv = *(const half4_t*)(&sA[1][r * SA + cg]);
        half4_t cv;
        #pragma unroll
        for (int t = 0; t < 4; t++)
            cv[t] = (_Float16)((S[cg + t] - (float)hv[t]) * (1.f / 32.f));
        *(half4_t*)(&sA[0][r * SA + cg]) = cv;
    }
    __syncthreads();

    // ---- GRU2: gi = c @ W_ih, gh = h1 @ W_hh; r/z gates chain both into one acc
    zero24(acc);
    gemm_tile4<8>(&sA[0][0], prep + WIH_OFF, 48, 0 + ntl0, wih, HID, use_prep, lane, acc);
    gemm_tile4<8>(&sA[1][0], prep + WHH_OFF, 48, 0 + ntl0, whh, HID, use_prep, lane, acc);
    #pragma unroll
    for (int nn = 0; nn < 4; nn++) {
        int col = (ntl0 + nn) * 16 + l16;
        float bb = b_ih[col] + b_hh[col];
        #pragma unroll
        for (int mt = 0; mt < 2; mt++)
            #pragma unroll
            for (int r = 0; r < 4; r++)
                rn[mt][nn][r] = sigmoid_f(acc[mt][nn][r] + bb);       // r-gate
    }
    zero24(acc);
    gemm_tile4<8>(&sA[1][0], prep + WHH_OFF, 48, 32 + ntl0, whh, HID, use_prep, lane, acc);
    #pragma unroll
    for (int nn = 0; nn < 4; nn++) {
        int col = (ntl0 + nn) * 16 + l16;
        float bh = b_hh[512 + col];
        #pragma unroll
        for (int mt = 0; mt < 2; mt++)
            #pragma unroll
            for (int r = 0; r < 4; r++)
                rn[mt][nn][r] = rn[mt][nn][r] * (acc[mt][nn][r] + bh); // r * (h_n)
    }
    zero24(acc);
    gemm_tile4<8>(&sA[0][0], prep + WIH_OFF, 48, 32 + ntl0, wih, HID, use_prep, lane, acc);
    #pragma unroll
    for (int nn = 0; nn < 4; nn++) {
        int col = (ntl0 + nn) * 16 + l16;
        float bi = b_ih[512 + col];
        #pragma unroll
        for (int mt = 0; mt < 2; mt++)
            #pragma unroll
            for (int r = 0; r < 4; r++)
                rn[mt][nn][r] = tanh_f(acc[mt][nn][r] + bi + rn[mt][nn][r]);  // n-gate
    }
    zero24(acc);
    gemm_tile4<8>(&sA[0][0], prep + WIH_OFF, 48, 16 + ntl0, wih, HID, use_prep, lane, acc);
    gemm_tile4<8>(&sA[1][0], prep + WHH_OFF, 48, 16 + ntl0, whh, HID, use_prep, lane, acc);
    float dw[4];
    #pragma unroll
    for (int nn = 0; nn < 4; nn++) dw[nn] = dec_W[(ntl0 + nn) * 16 + l16];
    float p[2][4] = {};
    #pragma unroll
    for (int nn = 0; nn < 4; nn++) {
        int col = (ntl0 + nn) * 16 + l16;
        float bb = b_ih[256 + col] + b_hh[256 + col];
        #pragma unroll
        for (int mt = 0; mt < 2; mt++)
            #pragma unroll
            for (int r = 0; r < 4; r++) {
                int row = mt * 16 + quad * 4 + r;
                float z = sigmoid_f(acc[mt][nn][r] + bb);
                float h1v = (float)sA[1][row * SA + col];
                float h2 = (1.f - z) * rn[mt][nn][r] + z * h1v;
                p[mt][r] += h2 * dw[nn];               // fuse decoder dot
            }
    }

    // ---- decoder reduce: sum over cols (l16 lanes) then across waves via LDS
    #pragma unroll
    for (int m = 1; m <= 8; m <<= 1)
        #pragma unroll
        for (int mt = 0; mt < 2; mt++)
            #pragma unroll
            for (int r = 0; r < 4; r++)
                p[mt][r] += __shfl_xor(p[mt][r], m);
    if (l16 == 0) {
        #pragma unroll
        for (int mt = 0; mt < 2; mt++)
            #pragma unroll
            for (int r = 0; r < 4; r++)
                atomicAdd(&D[mt * 16 + quad * 4 + r], p[mt][r]);
    }
    __syncthreads();
    if (tid < NA) out[(size_t)b * NA + tid] = D[tid] + dec_b[0];
}

extern "C" void kernel_launch(void* const* d_in, const int* in_sizes, int n_in,
                              void* d_out, int out_size, void* d_ws, size_t ws_size,
                              hipStream_t stream) {
    const float* obs   = (const float*)d_in[0];
    // d_in[1] (act) unused by reference
    const float* encW  = (const float*)d_in[2];
    const float* encb  = (const float*)d_in[3];
    const float* fobsW = (const float*)d_in[4];
    const float* fobsb = (const float*)d_in[5];
    const float* wih   = (const float*)d_in[6];
    const float* bih   = (const float*)d_in[7];
    const float* whh   = (const float*)d_in[8];
    const float* bhh   = (const float*)d_in[9];
    const float* decW  = (const float*)d_in[10];
    const float* decb  = (const float*)d_in[11];
    float* out = (float*)d_out;

    _Float16* prep = (_Float16*)d_ws;
    int use_prep = (ws_size >= (size_t)PREP_TOTAL * sizeof(_Float16)) ? 1 : 0;
    if (use_prep) {
        prep_weights<<<240, 256, 0, stream>>>(encW, fobsW, wih, whh, prep);
    }
    commnet_fused<<<NB, 256, 0, stream>>>(obs, prep, encb, fobsb, bih, bhh, decW, decb, out,
                                          encW, fobsW, wih, whh, use_prep);
}